// Round 11
// baseline (227.010 us; speedup 1.0000x reference)
//
#include <hip/hip_runtime.h>
#include <hip/hip_bf16.h>
#include <cstdint>
#include <cstddef>

// SupConLoss, N=16384 D=128, T=0.07, 100 classes.
// Round 2 (resubmit #9 after infra failures): pipelined triangular tiles.
// One block per (I-tile, J-chunk of 4); A fragments register-resident,
// B double-buffered via global_load_lds with staging issued before the
// previous tile's epilogue (latency hidden). Row/col sums -> device-wide
// float atomics; diagonal exp(1/T) analytic.

#define N_ROWS 16384
#define DIM    128
#define TILE   128
#define NTILES (N_ROWS / TILE)   // 128

// exp(sim/T) = exp2( dot * log2(e)/T ); bake sqrt(log2(e)/T) into features.
#define FEAT_SCALE 4.5398164f

typedef __attribute__((ext_vector_type(8))) short bf16x8;
typedef __attribute__((ext_vector_type(4))) float f32x4;

typedef const __attribute__((address_space(1))) unsigned int* gas_ptr;
typedef __attribute__((address_space(3))) unsigned int* las_ptr;

// ---------------------------------------------------------------- normalize
__global__ __launch_bounds__(256) void k_normalize(const float* __restrict__ F,
                                                   __hip_bfloat16* __restrict__ G) {
    int tid  = threadIdx.x;
    int lane = tid & 63;
    int wave = tid >> 6;
    int row  = blockIdx.x * 4 + wave;
    const float2* src = (const float2*)(F + (size_t)row * DIM) + lane;
    float2 x = *src;
    float s = x.x * x.x + x.y * x.y;
#pragma unroll
    for (int i = 1; i < 64; i <<= 1) s += __shfl_xor(s, i, 64);
    float scale = FEAT_SCALE / fmaxf(sqrtf(s), 1e-12f);
    __hip_bfloat162 h;
    h.x = __float2bfloat16(x.x * scale);
    h.y = __float2bfloat16(x.y * scale);
    ((__hip_bfloat162*)(G + (size_t)row * DIM))[lane] = h;
}

// ---------------------------------------------------------------- main tiles
// Block = (I, chunk c): I-tile rows, J-tiles J0..J0+nj-1 (nj<=4, J>=I).
// A(32KB) staged once -> register fragments; B double-buffered in the two
// 32KB LDS halves (A's half is reused after fragment extraction).
__global__ __launch_bounds__(256, 2) void k_tiles(const __hip_bfloat16* __restrict__ G,
                                                  const int* __restrict__ lab,
                                                  float* __restrict__ rN,
                                                  float* __restrict__ rT) {
    __shared__ __align__(16) char lds[65536 + 2048];
    float* sRed = (float*)(lds + 65536);   // 512 floats, reused col/row phases

    int tid = threadIdx.x;

    // ---- triangular decode: bid -> (I, chunk c) with c >= I/4
    int bid = blockIdx.x;
    int u = bid >> 2, i2 = bid & 3;
    int c = (int)((sqrtf(8.f * (float)u + 1.f) - 1.f) * 0.5f);
    while ((c + 1) * (c + 2) / 2 <= u) ++c;
    while (c * (c + 1) / 2 > u) --c;
    int g = u - c * (c + 1) / 2;          // g <= c
    int I = g * 4 + i2;
    int J0 = (I > c * 4) ? I : c * 4;
    int nj = c * 4 + 4 - J0;              // 1..4

    // ---- stage A -> lds[0,32K), B(J0) -> lds[32K,64K)  (pre-swizzled source)
    const char* gbase = (const char*)G;
    {
        const char* gA = gbase + (size_t)I * (TILE * DIM * 2);
        const char* gB = gbase + (size_t)J0 * (TILE * DIM * 2);
#pragma unroll
        for (int p = 0; p < 8; ++p) {
            int o = p * 4096 + tid * 16;
            int so = o ^ (((o >> 8) & 7) << 4);
            __builtin_amdgcn_global_load_lds((gas_ptr)(gA + so), (las_ptr)(lds + o), 16, 0, 0);
            __builtin_amdgcn_global_load_lds((gas_ptr)(gB + so), (las_ptr)(lds + 32768 + o), 16, 0, 0);
        }
    }

    int lane = tid & 63, w = tid >> 6;
    int wr = w >> 1, wc = w & 1;          // 2x2 waves of 64x64
    int lr = lane & 15, lhi = lane >> 4;

    __syncthreads();                      // drains vmcnt -> A,B0 resident

    // ---- A fragments to registers (64 VGPRs), row labels
    bf16x8 afr[4][4];                     // [m][kk]
#pragma unroll
    for (int m = 0; m < 4; ++m) {
        int row = wr * 64 + m * 16 + lr;
#pragma unroll
        for (int kk = 0; kk < 4; ++kk) {
            int lin = row * 256 + kk * 64 + lhi * 16;
            afr[m][kk] = *(const bf16x8*)(lds + (lin ^ ((row & 7) << 4)));
        }
    }
    int rowbase = I * TILE + wr * 64;
    int labr[4][4];
#pragma unroll
    for (int m = 0; m < 4; ++m)
#pragma unroll
        for (int r = 0; r < 4; ++r) labr[m][r] = lab[rowbase + m * 16 + lhi * 4 + r];

    float rn[4][4], rt[4][4];
#pragma unroll
    for (int m = 0; m < 4; ++m)
#pragma unroll
        for (int r = 0; r < 4; ++r) { rn[m][r] = 0.f; rt[m][r] = 0.f; }

    __syncthreads();                      // all waves done reading A region

    // ---- J loop, double-buffered B
    for (int t = 0; t < nj; ++t) {
        char* buf = lds + (((t & 1) ^ 1) << 15);   // B(t)
        int Jt = J0 + t;

        if (t + 1 < nj) {                 // issue B(t+1) early -> hidden
            const char* gB = gbase + (size_t)(Jt + 1) * (TILE * DIM * 2);
            char* nbuf = lds + ((t & 1) << 15);
#pragma unroll
            for (int p = 0; p < 8; ++p) {
                int o = p * 4096 + tid * 16;
                int so = o ^ (((o >> 8) & 7) << 4);
                __builtin_amdgcn_global_load_lds((gas_ptr)(gB + so), (las_ptr)(nbuf + o), 16, 0, 0);
            }
        }
        __builtin_amdgcn_sched_barrier(0);  // keep stage issue ahead of compute

        int colbase = Jt * TILE + wc * 64;
        int labc[4];
#pragma unroll
        for (int n = 0; n < 4; ++n) labc[n] = lab[colbase + n * 16 + lr];

        f32x4 acc[4][4];
#pragma unroll
        for (int m = 0; m < 4; ++m)
#pragma unroll
            for (int n = 0; n < 4; ++n) acc[m][n] = (f32x4){0.f, 0.f, 0.f, 0.f};

#pragma unroll
        for (int kk = 0; kk < 4; ++kk) {
            bf16x8 b[4];
#pragma unroll
            for (int n = 0; n < 4; ++n) {
                int row = wc * 64 + n * 16 + lr;
                int lin = row * 256 + kk * 64 + lhi * 16;
                b[n] = *(const bf16x8*)(buf + (lin ^ ((row & 7) << 4)));
            }
#pragma unroll
            for (int m = 0; m < 4; ++m)
#pragma unroll
                for (int n = 0; n < 4; ++n)
                    acc[m][n] = __builtin_amdgcn_mfma_f32_16x16x32_bf16(afr[m][kk], b[n], acc[m][n], 0, 0, 0);
        }

        // ---- fused epilogue
        float cn[4] = {0.f, 0.f, 0.f, 0.f}, ct[4] = {0.f, 0.f, 0.f, 0.f};
        bool isdiag = (Jt == I);
        if (isdiag) {
#pragma unroll
            for (int n = 0; n < 4; ++n) {
                int col = colbase + n * 16 + lr;
#pragma unroll
                for (int m = 0; m < 4; ++m) {
                    int row0 = rowbase + m * 16 + lhi * 4;
#pragma unroll
                    for (int r = 0; r < 4; ++r) {
                        float e = __builtin_amdgcn_exp2f(acc[m][n][r]);
                        float te = ((row0 + r) != col) ? e : 0.f;
                        float me = (labr[m][r] == labc[n]) ? te : 0.f;
                        rn[m][r] += me;  rt[m][r] += te;
                        cn[n]    += me;  ct[n]    += te;
                    }
                }
            }
        } else {
#pragma unroll
            for (int n = 0; n < 4; ++n) {
#pragma unroll
                for (int m = 0; m < 4; ++m) {
#pragma unroll
                    for (int r = 0; r < 4; ++r) {
                        float e = __builtin_amdgcn_exp2f(acc[m][n][r]);
                        float me = (labr[m][r] == labc[n]) ? e : 0.f;
                        rn[m][r] += me;  rt[m][r] += e;
                        cn[n]    += me;  ct[n]    += e;
                    }
                }
            }
        }

        // ---- col partials: reduce over lhi, combine 2 wr-waves, atomic
#pragma unroll
        for (int n = 0; n < 4; ++n) {
            float v1 = cn[n], v2 = ct[n];
            v1 += __shfl_xor(v1, 16, 64); v1 += __shfl_xor(v1, 32, 64);
            v2 += __shfl_xor(v2, 16, 64); v2 += __shfl_xor(v2, 32, 64);
            if (lhi == 0) {
                int colt = wc * 64 + n * 16 + lr;
                sRed[wr * 128 + colt]       = v1;
                sRed[256 + wr * 128 + colt] = v2;
            }
        }
        __syncthreads();                  // also drains B(t+1) staging (done by now)
        if (!isdiag && tid < 128) {
            float num = sRed[tid] + sRed[128 + tid];
            float tot = sRed[256 + tid] + sRed[384 + tid];
            int col = Jt * TILE + tid;
            atomicAdd(&rN[col], num);
            atomicAdd(&rT[col], tot);
        }
        __syncthreads();                  // sRed free for next tile
    }

    // ---- row partials: reduce over lr once per block
#pragma unroll
    for (int m = 0; m < 4; ++m)
#pragma unroll
        for (int r = 0; r < 4; ++r) {
            float v1 = rn[m][r], v2 = rt[m][r];
#pragma unroll
            for (int s = 1; s < 16; s <<= 1) {
                v1 += __shfl_xor(v1, s, 64);
                v2 += __shfl_xor(v2, s, 64);
            }
            if (lr == 0) {
                int rowt = wr * 64 + m * 16 + lhi * 4 + r;
                sRed[wc * 128 + rowt]       = v1;
                sRed[256 + wc * 128 + rowt] = v2;
            }
        }
    __syncthreads();
    if (tid < 128) {
        float num = sRed[tid] + sRed[128 + tid];
        float tot = sRed[256 + tid] + sRed[384 + tid];
        int row = I * TILE + tid;
        atomicAdd(&rN[row], num);
        atomicAdd(&rT[row], tot);
    }
}

// ---------------------------------------------------------------- loss + mean
__global__ __launch_bounds__(256) void k_rowloss(const float* __restrict__ rN,
                                                 const float* __restrict__ rT,
                                                 float* __restrict__ accum) {
    int row = blockIdx.x * 256 + threadIdx.x;
    float num = rN[row], tot = rT[row];
    float ediag = expf(14.285714285714286f);       // exp(1/T), exact diagonal
    float denom = tot - num + ediag;
    float loss = -logf(num / denom + 1e-8f);
#pragma unroll
    for (int i = 1; i < 64; i <<= 1) loss += __shfl_xor(loss, i, 64);
    __shared__ float red[4];
    if ((threadIdx.x & 63) == 0) red[threadIdx.x >> 6] = loss;
    __syncthreads();
    if (threadIdx.x == 0)
        atomicAdd(accum, red[0] + red[1] + red[2] + red[3]);
}

__global__ void k_final(const float* __restrict__ accum, float* __restrict__ out) {
    out[0] = accum[0] / (float)N_ROWS;
}

// ---------------------------------------------------------------- launcher
extern "C" void kernel_launch(void* const* d_in, const int* in_sizes, int n_in,
                              void* d_out, int out_size, void* d_ws, size_t ws_size,
                              hipStream_t stream) {
    const float* F  = (const float*)d_in[0];
    const int* lab  = (const int*)d_in[1];
    float* out      = (float*)d_out;
    char* ws        = (char*)d_ws;

    __hip_bfloat16* G = (__hip_bfloat16*)ws;                 // 4 MB
    float* rN    = (float*)(ws + (4 << 20));                 // 64 KB
    float* rT    = rN + N_ROWS;                              // 64 KB
    float* accum = rT + N_ROWS;                              // 4 B

    k_normalize<<<N_ROWS / 4, 256, 0, stream>>>(F, G);
    hipMemsetAsync(rN, 0, (size_t)N_ROWS * 2 * sizeof(float) + 16, stream);

    int nblocks = 2112;   // sum over I-tiles of #4-wide J-chunks (triangle)
    k_tiles<<<nblocks, 256, 0, stream>>>(G, lab, rN, rT);

    k_rowloss<<<N_ROWS / 256, 256, 0, stream>>>(rN, rT, accum);
    k_final<<<1, 1, 0, stream>>>(accum, out);
}